// Round 5
// baseline (84.458 us; speedup 1.0000x reference)
//
#include <hip/hip_runtime.h>
#include <math.h>

// Problem constants (from reference): N=4, C=128, H=W=256, G=4, K=5, DIL=1
#define NB   4
#define CC   128
#define HH   256
#define WW   256
#define HWSZ (HH * WW)          // 65536
#define NC   (NB * CC)          // 512
#define GK   20                 // G*K

__device__ __forceinline__ float wave_reduce_sum(float v) {
#pragma unroll
    for (int o = 1; o < 64; o <<= 1) v += __shfl_xor(v, o, 64);
    return v;
}

// ---------------------------------------------------------------------------
// Kernel 1: per-(n,c) plane reductions: rowsum[h], colsum[w], planesum.
// One block per plane. Wave wv owns rows [64wv, 64wv+64), 4 rows/iter so the
// 4 shuffle-reduce chains interleave (ILP) and hide under the HBM stream.
// rowsum packed as one float4 store per 4 rows from lane 0.
// ---------------------------------------------------------------------------
__global__ __launch_bounds__(256) void k_reduce(const float4* __restrict__ x4,
                                                float* __restrict__ rowsum,
                                                float* __restrict__ colsum,
                                                float* __restrict__ planesum) {
    const int b = blockIdx.x;            // (n,c) index
    const int t = threadIdx.x;
    const int wv = t >> 6;               // wave id 0..3
    const int l = t & 63;                // lane
    const float4* plane = x4 + (size_t)b * (HWSZ / 4);
    const int r0 = wv * 64;

    float4 cs = make_float4(0.f, 0.f, 0.f, 0.f);
    for (int it = 0; it < 16; ++it) {
        const int r = r0 + 4 * it;
        float4 v0 = plane[(r + 0) * (WW / 4) + l];
        float4 v1 = plane[(r + 1) * (WW / 4) + l];
        float4 v2 = plane[(r + 2) * (WW / 4) + l];
        float4 v3 = plane[(r + 3) * (WW / 4) + l];
        cs.x += (v0.x + v1.x) + (v2.x + v3.x);
        cs.y += (v0.y + v1.y) + (v2.y + v3.y);
        cs.z += (v0.z + v1.z) + (v2.z + v3.z);
        cs.w += (v0.w + v1.w) + (v2.w + v3.w);
        float p0 = (v0.x + v0.y) + (v0.z + v0.w);
        float p1 = (v1.x + v1.y) + (v1.z + v1.w);
        float p2 = (v2.x + v2.y) + (v2.z + v2.w);
        float p3 = (v3.x + v3.y) + (v3.z + v3.w);
        p0 = wave_reduce_sum(p0);
        p1 = wave_reduce_sum(p1);
        p2 = wave_reduce_sum(p2);
        p3 = wave_reduce_sum(p3);
        if (l == 0) *(float4*)&rowsum[b * HH + r] = make_float4(p0, p1, p2, p3);
    }

    __shared__ float colpart[4][WW];
    colpart[wv][4 * l + 0] = cs.x;
    colpart[wv][4 * l + 1] = cs.y;
    colpart[wv][4 * l + 2] = cs.z;
    colpart[wv][4 * l + 3] = cs.w;
    __syncthreads();
    float c = (colpart[0][t] + colpart[1][t]) + (colpart[2][t] + colpart[3][t]);
    colsum[b * WW + t] = c;

    float p = wave_reduce_sum(c);
    __shared__ float pr[4];
    if (l == 0) pr[wv] = p;
    __syncthreads();
    if (t == 0) planesum[b] = (pr[0] + pr[1]) + (pr[2] + pr[3]);
}

// ---------------------------------------------------------------------------
// Kernel 2: tiny (R2-proven). f_h = tanh(conv_h @ mean_x); analytic
// mean(out1); f_v = tanh(conv_v @ mean_out1). Single block, 256 threads.
// Reflect-pad boundary corrections for the horizontal conv plane-mean:
//   k=0 (shift -2): S + c1 + c2 - c254 - c255
//   k=1 (shift -1): S + c1 - c255
//   k=2 (shift  0): S
//   k=3 (shift +1): S + c254 - c0
//   k=4 (shift +2): S + c253 + c254 - c0 - c1
// ---------------------------------------------------------------------------
__global__ __launch_bounds__(256) void k_small(const float* __restrict__ colsum,
                                               const float* __restrict__ planesum,
                                               const float* __restrict__ conv_h,
                                               const float* __restrict__ inside_h,
                                               const float* __restrict__ lamb_l_h,
                                               const float* __restrict__ lamb_h_h,
                                               const float* __restrict__ conv_v,
                                               float* __restrict__ f_h_out,
                                               float* __restrict__ f_v_out) {
    __shared__ float meanx[NC];
    __shared__ float fh[NB * GK];
    __shared__ float mo1[NC];
    const int t = threadIdx.x;

    for (int i = t; i < NC; i += 256) meanx[i] = planesum[i] * (1.f / HWSZ);
    __syncthreads();

    if (t < NB * GK) {
        const int n = t / GK, o = t % GK;
        float acc = 0.f;
        for (int c = 0; c < CC; ++c) acc += meanx[n * CC + c] * conv_h[o * CC + c];
        float v = tanhf(acc);
        fh[t] = v;
        f_h_out[t] = v;
    }
    __syncthreads();

    for (int i = t; i < NC; i += 256) {
        const int n = i >> 7, c = i & (CC - 1), g = c >> 5;
        const float* f = &fh[n * GK + g * 5];
        const float S = planesum[i];
        const float* col = colsum + i * WW;
        const float c0 = col[0], c1 = col[1], c2 = col[2];
        const float c253 = col[253], c254 = col[254], c255 = col[255];
        const float s0 = S + c1 + c2 - c254 - c255;
        const float s1 = S + c1 - c255;
        const float s2 = S;
        const float s3 = S + c254 - c0;
        const float s4 = S + c253 + c254 - c0 - c1;
        const float convmean =
            (f[0] * s0 + f[1] * s1 + f[2] * s2 + f[3] * s3 + f[4] * s4) * (1.f / HWSZ);
        const float A = (inside_h[c] + 1.f) * lamb_l_h[c];
        const float B = inside_h[c] * lamb_l_h[c];
        const float Cq = lamb_h_h[c] + 1.f;
        mo1[i] = A * convmean + (Cq - B) * meanx[i];
    }
    __syncthreads();

    if (t < NB * GK) {
        const int n = t / GK, o = t % GK;
        float acc = 0.f;
        for (int c = 0; c < CC; ++c) acc += mo1[n * CC + c] * conv_v[o * CC + c];
        f_v_out[t] = tanhf(acc);
    }
}

// ---------------------------------------------------------------------------
// Kernel 3: fused main pass — ZERO LDS / shuffles / barriers in main loop.
// Each wave owns a 32-row vertical strip; rows stream top-to-bottom.
// Horizontal 5-tap: aligned float4 + two 8B loads at +/-2 floats (L1 hits).
// Vertical 5-tap: 4 staggered accumulators; the ring shift is fused into the
// FMA cascade. Own-row terms (gm*Cv*hc + bt*x) and the constant (-gm*Bv*gx)
// fold into the accumulator coefficients:
//   out(j-2) = acc0 + K4*hc          K4  = gm*Av*fv4
//   acc0 = acc1 + K3*hc              K3  = gm*Av*fv3
//   acc1 = acc2 + K2p*hc + bt*x      K2p = gm*(Av*fv2 + Cv)
//   acc2 = acc3 + K1*hc              K1  = gm*Av*fv1
//   acc3 = K0*hc + Dg                K0  = gm*Av*fv0, Dg = -gm*Bv*gx
// ---------------------------------------------------------------------------
__global__ __launch_bounds__(256) void k_main(const float* __restrict__ x,
                                              const float* __restrict__ rowsum,
                                              const float* __restrict__ colsum,
                                              const float* __restrict__ planesum,
                                              const float* __restrict__ f_h,
                                              const float* __restrict__ f_v,
                                              const float* __restrict__ inside_h,
                                              const float* __restrict__ lamb_l_h,
                                              const float* __restrict__ lamb_h_h,
                                              const float* __restrict__ inside_v,
                                              const float* __restrict__ lamb_l_v,
                                              const float* __restrict__ lamb_h_v,
                                              const float* __restrict__ gamma,
                                              const float* __restrict__ beta,
                                              float* __restrict__ out) {
    const int b = blockIdx.x >> 1;        // (n,c)
    const int half = blockIdx.x & 1;      // row half 0..1
    const int n = b >> 7, c = b & (CC - 1), g = c >> 5;
    const int t = threadIdx.x;
    const int wv = t >> 6;                // wave id 0..3
    const int l = t & 63;                 // lane

    float fh[5], fv[5];
#pragma unroll
    for (int k = 0; k < 5; ++k) {
        fh[k] = f_h[n * GK + g * 5 + k];
        fv[k] = f_v[n * GK + g * 5 + k];
    }
    const float Ah = (inside_h[c] + 1.f) * lamb_l_h[c];
    const float Bh = inside_h[c] * lamb_l_h[c];
    const float Ch = lamb_h_h[c] + 1.f;
    const float Av = (inside_v[c] + 1.f) * lamb_l_v[c];
    const float Bv = inside_v[c] * lamb_l_v[c];
    const float Cv = lamb_h_v[c] + 1.f;
    const float gm = gamma[c], bt = beta[c];
    const float meanx = planesum[b] * (1.f / HWSZ);

    // --- gapx_v per column (reflect-padded 5-tap over column means of x,
    //     pushed through the stage-1 affine map), folded into Dg ---
    __shared__ float lcol[WW + 4];
    lcol[t + 2] = colsum[b * WW + t] * (1.f / HH);
    if (t < 2) lcol[t] = colsum[b * WW + (2 - t)] * (1.f / HH);
    if (t >= WW - 2) lcol[t + 4] = colsum[b * WW + (2 * WW - 4 - t)] * (1.f / HH);
    __syncthreads();

    float Dg0, Dg1, Dg2, Dg3;
    {
        float q[8];
#pragma unroll
        for (int d = 0; d < 8; ++d) q[d] = lcol[4 * l + d];
        float gxv[4];
#pragma unroll
        for (int d = 0; d < 4; ++d) {
            gxv[d] = Ah * (fh[0] * q[d] + fh[1] * q[d + 1] + fh[2] * q[d + 2] +
                           fh[3] * q[d + 3] + fh[4] * q[d + 4]) -
                     Bh * meanx + Ch * q[d + 2];
        }
        const float nGB = -gm * Bv;
        Dg0 = nGB * gxv[0]; Dg1 = nGB * gxv[1];
        Dg2 = nGB * gxv[2]; Dg3 = nGB * gxv[3];
    }

    const float K4 = gm * Av * fv[4];
    const float K3 = gm * Av * fv[3];
    const float K2p = gm * (Av * fv[2] + Cv);
    const float K1 = gm * Av * fv[1];
    const float K0 = gm * Av * fv[0];

    const float* plane = x + (size_t)b * HWSZ;
    float* oplane = out + (size_t)b * HWSZ;
    const float* rsb = rowsum + b * HH;
    const int r0 = half * 128 + wv * 32;  // this wave's first owned row

    const int offa = (l == 0) ? 0 : 4 * l - 2;     // 8B-aligned, in-bounds
    const int offb = (l == 63) ? 248 : 4 * l + 4;  // edge lanes: value unused

    auto refl = [](int h) { return h < 0 ? -h : (h > HH - 1 ? 2 * HH - 2 - h : h); };

    // prefetch row for i=0 (stream position r0-2)
    int hr = refl(r0 - 2);
    const float* rp = plane + hr * WW;
    float4 v = *(const float4*)(rp + 4 * l);
    float2 a = *(const float2*)(rp + offa);
    float2 bb = *(const float2*)(rp + offb);
    float rs = rsb[hr];

    float4 acc0 = {0, 0, 0, 0}, acc1 = {0, 0, 0, 0};
    float4 acc2 = {0, 0, 0, 0}, acc3 = {0, 0, 0, 0};

    for (int i = 0; i < 36; ++i) {
        const float4 vc = v;
        const float2 ac = a, bc = bb;
        const float rsc = rs;
        if (i < 35) {                     // prefetch next stream row
            const int h2 = refl(r0 - 1 + i);
            const float* rp2 = plane + h2 * WW;
            v = *(const float4*)(rp2 + 4 * l);
            a = *(const float2*)(rp2 + offa);
            bb = *(const float2*)(rp2 + offb);
            rs = rsb[h2];
        }
        const float gh = rsc * (1.f / WW);

        const float m2 = (l == 0) ? vc.z : ac.x;   // x[-2]=x[2]
        const float m1 = (l == 0) ? vc.y : ac.y;   // x[-1]=x[1]
        const float p4 = (l == 63) ? vc.z : bc.x;  // x[256]=x[254]
        const float p5 = (l == 63) ? vc.y : bc.y;  // x[257]=x[253]

        const float h0v = fh[0] * m2 + fh[1] * m1 + fh[2] * vc.x + fh[3] * vc.y + fh[4] * vc.z;
        const float h1v = fh[0] * m1 + fh[1] * vc.x + fh[2] * vc.y + fh[3] * vc.z + fh[4] * vc.w;
        const float h2v = fh[0] * vc.x + fh[1] * vc.y + fh[2] * vc.z + fh[3] * vc.w + fh[4] * p4;
        const float h3v = fh[0] * vc.y + fh[1] * vc.z + fh[2] * vc.w + fh[3] * p4 + fh[4] * p5;

        float4 hc;                        // stage-1 output row (out1)
        hc.x = Ah * h0v - Bh * gh + Ch * vc.x;
        hc.y = Ah * h1v - Bh * gh + Ch * vc.y;
        hc.z = Ah * h2v - Bh * gh + Ch * vc.z;
        hc.w = Ah * h3v - Bh * gh + Ch * vc.w;

        if (i >= 4) {                     // output row r0+i-4 completes
            float4 o;
            o.x = acc0.x + K4 * hc.x;
            o.y = acc0.y + K4 * hc.y;
            o.z = acc0.z + K4 * hc.z;
            o.w = acc0.w + K4 * hc.w;
            *(float4*)&oplane[(r0 + i - 4) * WW + 4 * l] = o;
        }
        acc0.x = acc1.x + K3 * hc.x;
        acc0.y = acc1.y + K3 * hc.y;
        acc0.z = acc1.z + K3 * hc.z;
        acc0.w = acc1.w + K3 * hc.w;
        acc1.x = acc2.x + K2p * hc.x + bt * vc.x;
        acc1.y = acc2.y + K2p * hc.y + bt * vc.y;
        acc1.z = acc2.z + K2p * hc.z + bt * vc.z;
        acc1.w = acc2.w + K2p * hc.w + bt * vc.w;
        acc2.x = acc3.x + K1 * hc.x;
        acc2.y = acc3.y + K1 * hc.y;
        acc2.z = acc3.z + K1 * hc.z;
        acc2.w = acc3.w + K1 * hc.w;
        acc3.x = K0 * hc.x + Dg0;
        acc3.y = K0 * hc.y + Dg1;
        acc3.z = K0 * hc.z + Dg2;
        acc3.w = K0 * hc.w + Dg3;
    }
}

// ---------------------------------------------------------------------------
extern "C" void kernel_launch(void* const* d_in, const int* in_sizes, int n_in,
                              void* d_out, int out_size, void* d_ws, size_t ws_size,
                              hipStream_t stream) {
    const float* x        = (const float*)d_in[0];
    const float* conv_h   = (const float*)d_in[1];
    const float* inside_h = (const float*)d_in[2];
    const float* lamb_l_h = (const float*)d_in[3];
    const float* lamb_h_h = (const float*)d_in[4];
    const float* conv_v   = (const float*)d_in[5];
    const float* inside_v = (const float*)d_in[6];
    const float* lamb_l_v = (const float*)d_in[7];
    const float* lamb_h_v = (const float*)d_in[8];
    const float* gamma    = (const float*)d_in[9];
    const float* beta     = (const float*)d_in[10];
    float* out = (float*)d_out;

    float* ws = (float*)d_ws;
    float* rowsum   = ws;                 // NC*HH = 131072
    float* colsum   = ws + 131072;        // NC*WW = 131072
    float* planesum = ws + 262144;        // NC    = 512
    float* f_h      = ws + 262656;        // 80
    float* f_v      = ws + 262736;        // 80

    k_reduce<<<NC, 256, 0, stream>>>((const float4*)x, rowsum, colsum, planesum);
    k_small<<<1, 256, 0, stream>>>(colsum, planesum, conv_h, inside_h, lamb_l_h,
                                   lamb_h_h, conv_v, f_h, f_v);
    k_main<<<NC * 2, 256, 0, stream>>>(x, rowsum, colsum, planesum, f_h, f_v,
                                       inside_h, lamb_l_h, lamb_h_h,
                                       inside_v, lamb_l_v, lamb_h_v,
                                       gamma, beta, out);
}

// Round 7
// 82.716 us; speedup vs baseline: 1.0211x; 1.0211x over previous
//
#include <hip/hip_runtime.h>
#include <math.h>

// Problem constants (from reference): N=4, C=128, H=W=256, G=4, K=5, DIL=1
#define NB   4
#define CC   128
#define HH   256
#define WW   256
#define HWSZ (HH * WW)          // 65536
#define NC   (NB * CC)          // 512
#define GK   20                 // G*K

typedef float floatx4 __attribute__((ext_vector_type(4)));

__device__ __forceinline__ float wave_reduce_sum(float v) {
#pragma unroll
    for (int o = 1; o < 64; o <<= 1) v += __shfl_xor(v, o, 64);
    return v;
}

// ---------------------------------------------------------------------------
// Kernel 1: per-(n,c) plane reductions: rowsum[h], colsum[w], planesum.
// One block per plane. Wave wv owns rows [64wv, 64wv+64), 4 rows/iter so the
// 4 shuffle-reduce chains interleave (ILP) and hide under the HBM stream.
// ---------------------------------------------------------------------------
__global__ __launch_bounds__(256) void k_reduce(const float4* __restrict__ x4,
                                                float* __restrict__ rowsum,
                                                float* __restrict__ colsum,
                                                float* __restrict__ planesum) {
    const int b = blockIdx.x;            // (n,c) index
    const int t = threadIdx.x;
    const int wv = t >> 6;               // wave id 0..3
    const int l = t & 63;                // lane
    const float4* plane = x4 + (size_t)b * (HWSZ / 4);
    const int r0 = wv * 64;

    float4 cs = make_float4(0.f, 0.f, 0.f, 0.f);
    for (int it = 0; it < 16; ++it) {
        const int r = r0 + 4 * it;
        float4 v0 = plane[(r + 0) * (WW / 4) + l];
        float4 v1 = plane[(r + 1) * (WW / 4) + l];
        float4 v2 = plane[(r + 2) * (WW / 4) + l];
        float4 v3 = plane[(r + 3) * (WW / 4) + l];
        cs.x += (v0.x + v1.x) + (v2.x + v3.x);
        cs.y += (v0.y + v1.y) + (v2.y + v3.y);
        cs.z += (v0.z + v1.z) + (v2.z + v3.z);
        cs.w += (v0.w + v1.w) + (v2.w + v3.w);
        float p0 = (v0.x + v0.y) + (v0.z + v0.w);
        float p1 = (v1.x + v1.y) + (v1.z + v1.w);
        float p2 = (v2.x + v2.y) + (v2.z + v2.w);
        float p3 = (v3.x + v3.y) + (v3.z + v3.w);
        p0 = wave_reduce_sum(p0);
        p1 = wave_reduce_sum(p1);
        p2 = wave_reduce_sum(p2);
        p3 = wave_reduce_sum(p3);
        if (l == 0) *(float4*)&rowsum[b * HH + r] = make_float4(p0, p1, p2, p3);
    }

    __shared__ float colpart[4][WW];
    colpart[wv][4 * l + 0] = cs.x;
    colpart[wv][4 * l + 1] = cs.y;
    colpart[wv][4 * l + 2] = cs.z;
    colpart[wv][4 * l + 3] = cs.w;
    __syncthreads();
    float c = (colpart[0][t] + colpart[1][t]) + (colpart[2][t] + colpart[3][t]);
    colsum[b * WW + t] = c;

    float p = wave_reduce_sum(c);
    __shared__ float pr[4];
    if (l == 0) pr[wv] = p;
    __syncthreads();
    if (t == 0) planesum[b] = (pr[0] + pr[1]) + (pr[2] + pr[3]);
}

// ---------------------------------------------------------------------------
// Kernel 2: tiny (R2-proven). f_h = tanh(conv_h @ mean_x); analytic
// mean(out1); f_v = tanh(conv_v @ mean_out1). Single block, 256 threads.
// Reflect-pad boundary corrections for the horizontal conv plane-mean:
//   k=0 (shift -2): S + c1 + c2 - c254 - c255
//   k=1 (shift -1): S + c1 - c255
//   k=2 (shift  0): S
//   k=3 (shift +1): S + c254 - c0
//   k=4 (shift +2): S + c253 + c254 - c0 - c1
// ---------------------------------------------------------------------------
__global__ __launch_bounds__(256) void k_small(const float* __restrict__ colsum,
                                               const float* __restrict__ planesum,
                                               const float* __restrict__ conv_h,
                                               const float* __restrict__ inside_h,
                                               const float* __restrict__ lamb_l_h,
                                               const float* __restrict__ lamb_h_h,
                                               const float* __restrict__ conv_v,
                                               float* __restrict__ f_h_out,
                                               float* __restrict__ f_v_out) {
    __shared__ float meanx[NC];
    __shared__ float fh[NB * GK];
    __shared__ float mo1[NC];
    const int t = threadIdx.x;

    for (int i = t; i < NC; i += 256) meanx[i] = planesum[i] * (1.f / HWSZ);
    __syncthreads();

    if (t < NB * GK) {
        const int n = t / GK, o = t % GK;
        float acc = 0.f;
        for (int c = 0; c < CC; ++c) acc += meanx[n * CC + c] * conv_h[o * CC + c];
        float v = tanhf(acc);
        fh[t] = v;
        f_h_out[t] = v;
    }
    __syncthreads();

    for (int i = t; i < NC; i += 256) {
        const int n = i >> 7, c = i & (CC - 1), g = c >> 5;
        const float* f = &fh[n * GK + g * 5];
        const float S = planesum[i];
        const float* col = colsum + i * WW;
        const float c0 = col[0], c1 = col[1], c2 = col[2];
        const float c253 = col[253], c254 = col[254], c255 = col[255];
        const float s0 = S + c1 + c2 - c254 - c255;
        const float s1 = S + c1 - c255;
        const float s2 = S;
        const float s3 = S + c254 - c0;
        const float s4 = S + c253 + c254 - c0 - c1;
        const float convmean =
            (f[0] * s0 + f[1] * s1 + f[2] * s2 + f[3] * s3 + f[4] * s4) * (1.f / HWSZ);
        const float A = (inside_h[c] + 1.f) * lamb_l_h[c];
        const float B = inside_h[c] * lamb_l_h[c];
        const float Cq = lamb_h_h[c] + 1.f;
        mo1[i] = A * convmean + (Cq - B) * meanx[i];
    }
    __syncthreads();

    if (t < NB * GK) {
        const int n = t / GK, o = t % GK;
        float acc = 0.f;
        for (int c = 0; c < CC; ++c) acc += mo1[n * CC + c] * conv_v[o * CC + c];
        f_v_out[t] = tanhf(acc);
    }
}

// ---------------------------------------------------------------------------
// Kernel 3: fused main pass — register cascade (R5-proven math), fixed for
// occupancy + VMEM count: 2048 blocks (16-row strip per wave), horizontal
// neighbors via 4 shuffles (single float4 VMEM load per row), rowsum via
// readfirstlane scalar load, nontemporal output stores (keep x L3-resident).
//   out(s-2) = acc0 + K4*hc          K4  = gm*Av*fv4
//   acc0 = acc1 + K3*hc              K3  = gm*Av*fv3
//   acc1 = acc2 + K2p*hc + bt*x      K2p = gm*(Av*fv2 + Cv)
//   acc2 = acc3 + K1*hc              K1  = gm*Av*fv1
//   acc3 = K0*hc + Dg                K0  = gm*Av*fv0, Dg = -gm*Bv*gx
// ---------------------------------------------------------------------------
__global__ __launch_bounds__(256) void k_main(const float* __restrict__ x,
                                              const float* __restrict__ rowsum,
                                              const float* __restrict__ colsum,
                                              const float* __restrict__ planesum,
                                              const float* __restrict__ f_h,
                                              const float* __restrict__ f_v,
                                              const float* __restrict__ inside_h,
                                              const float* __restrict__ lamb_l_h,
                                              const float* __restrict__ lamb_h_h,
                                              const float* __restrict__ inside_v,
                                              const float* __restrict__ lamb_l_v,
                                              const float* __restrict__ lamb_h_v,
                                              const float* __restrict__ gamma,
                                              const float* __restrict__ beta,
                                              float* __restrict__ out) {
    const int b = blockIdx.x >> 2;        // (n,c)
    const int tile = blockIdx.x & 3;      // 64-row tile
    const int n = b >> 7, c = b & (CC - 1), g = c >> 5;
    const int t = threadIdx.x;
    const int wv = t >> 6;                // wave id 0..3
    const int l = t & 63;                 // lane

    float fh[5], fv[5];
#pragma unroll
    for (int k = 0; k < 5; ++k) {
        fh[k] = f_h[n * GK + g * 5 + k];
        fv[k] = f_v[n * GK + g * 5 + k];
    }
    const float Ah = (inside_h[c] + 1.f) * lamb_l_h[c];
    const float Bh = inside_h[c] * lamb_l_h[c];
    const float Ch = lamb_h_h[c] + 1.f;
    const float Av = (inside_v[c] + 1.f) * lamb_l_v[c];
    const float Bv = inside_v[c] * lamb_l_v[c];
    const float Cv = lamb_h_v[c] + 1.f;
    const float gm = gamma[c], bt = beta[c];
    const float meanx = planesum[b] * (1.f / HWSZ);

    // --- gapx_v per column (reflect-padded 5-tap over column means of x,
    //     pushed through the stage-1 affine map), folded into Dg ---
    __shared__ float lcol[WW + 4];
    lcol[t + 2] = colsum[b * WW + t] * (1.f / HH);
    if (t < 2) lcol[t] = colsum[b * WW + (2 - t)] * (1.f / HH);
    if (t >= WW - 2) lcol[t + 4] = colsum[b * WW + (2 * WW - 4 - t)] * (1.f / HH);
    __syncthreads();

    float Dg0, Dg1, Dg2, Dg3;
    {
        float q[8];
#pragma unroll
        for (int d = 0; d < 8; ++d) q[d] = lcol[4 * l + d];
        float gxv[4];
#pragma unroll
        for (int d = 0; d < 4; ++d) {
            gxv[d] = Ah * (fh[0] * q[d] + fh[1] * q[d + 1] + fh[2] * q[d + 2] +
                           fh[3] * q[d + 3] + fh[4] * q[d + 4]) -
                     Bh * meanx + Ch * q[d + 2];
        }
        const float nGB = -gm * Bv;
        Dg0 = nGB * gxv[0]; Dg1 = nGB * gxv[1];
        Dg2 = nGB * gxv[2]; Dg3 = nGB * gxv[3];
    }

    const float K4 = gm * Av * fv[4];
    const float K3 = gm * Av * fv[3];
    const float K2p = gm * (Av * fv[2] + Cv);
    const float K1 = gm * Av * fv[1];
    const float K0 = gm * Av * fv[0];

    const float* plane = x + (size_t)b * HWSZ;
    float* oplane = out + (size_t)b * HWSZ;
    const float* rsb = rowsum + b * HH;
    const int r0 = tile * 64 + wv * 16;   // this wave's first owned row

    auto refl = [](int h) { return h < 0 ? -h : (h > HH - 1 ? 2 * HH - 2 - h : h); };

    // prefetch stream row for i=0 (position r0-2)
    int hr = refl(r0 - 2);
    float4 v = *(const float4*)(plane + hr * WW + 4 * l);
    float rs = rsb[__builtin_amdgcn_readfirstlane(hr)];   // wave-uniform -> s_load

    float4 acc0 = {0, 0, 0, 0}, acc1 = {0, 0, 0, 0};
    float4 acc2 = {0, 0, 0, 0}, acc3 = {0, 0, 0, 0};

    for (int i = 0; i < 20; ++i) {
        const float4 vc = v;
        const float rsc = rs;
        if (i < 19) {                     // prefetch next stream row
            const int h2 = refl(r0 - 1 + i);
            v = *(const float4*)(plane + h2 * WW + 4 * l);
            rs = rsb[__builtin_amdgcn_readfirstlane(h2)];
        }
        const float gh = rsc * (1.f / WW);

        // horizontal neighbors via shuffles; reflect edges from own regs
        float m2 = __shfl_up(vc.z, 1);
        float m1 = __shfl_up(vc.w, 1);
        float p4 = __shfl_down(vc.x, 1);
        float p5 = __shfl_down(vc.y, 1);
        if (l == 0)  { m2 = vc.z; m1 = vc.y; }   // x[-2]=x[2], x[-1]=x[1]
        if (l == 63) { p4 = vc.z; p5 = vc.y; }   // x[256]=x[254], x[257]=x[253]

        const float h0v = fh[0] * m2 + fh[1] * m1 + fh[2] * vc.x + fh[3] * vc.y + fh[4] * vc.z;
        const float h1v = fh[0] * m1 + fh[1] * vc.x + fh[2] * vc.y + fh[3] * vc.z + fh[4] * vc.w;
        const float h2v = fh[0] * vc.x + fh[1] * vc.y + fh[2] * vc.z + fh[3] * vc.w + fh[4] * p4;
        const float h3v = fh[0] * vc.y + fh[1] * vc.z + fh[2] * vc.w + fh[3] * p4 + fh[4] * p5;

        float4 hc;                        // stage-1 output row (out1)
        hc.x = Ah * h0v - Bh * gh + Ch * vc.x;
        hc.y = Ah * h1v - Bh * gh + Ch * vc.y;
        hc.z = Ah * h2v - Bh * gh + Ch * vc.z;
        hc.w = Ah * h3v - Bh * gh + Ch * vc.w;

        if (i >= 4) {                     // output row r0+i-4 completes
            floatx4 o;
            o.x = acc0.x + K4 * hc.x;
            o.y = acc0.y + K4 * hc.y;
            o.z = acc0.z + K4 * hc.z;
            o.w = acc0.w + K4 * hc.w;
            __builtin_nontemporal_store(o, (floatx4*)&oplane[(r0 + i - 4) * WW + 4 * l]);
        }
        acc0.x = acc1.x + K3 * hc.x;
        acc0.y = acc1.y + K3 * hc.y;
        acc0.z = acc1.z + K3 * hc.z;
        acc0.w = acc1.w + K3 * hc.w;
        acc1.x = acc2.x + K2p * hc.x + bt * vc.x;
        acc1.y = acc2.y + K2p * hc.y + bt * vc.y;
        acc1.z = acc2.z + K2p * hc.z + bt * vc.z;
        acc1.w = acc2.w + K2p * hc.w + bt * vc.w;
        acc2.x = acc3.x + K1 * hc.x;
        acc2.y = acc3.y + K1 * hc.y;
        acc2.z = acc3.z + K1 * hc.z;
        acc2.w = acc3.w + K1 * hc.w;
        acc3.x = K0 * hc.x + Dg0;
        acc3.y = K0 * hc.y + Dg1;
        acc3.z = K0 * hc.z + Dg2;
        acc3.w = K0 * hc.w + Dg3;
    }
}

// ---------------------------------------------------------------------------
extern "C" void kernel_launch(void* const* d_in, const int* in_sizes, int n_in,
                              void* d_out, int out_size, void* d_ws, size_t ws_size,
                              hipStream_t stream) {
    const float* x        = (const float*)d_in[0];
    const float* conv_h   = (const float*)d_in[1];
    const float* inside_h = (const float*)d_in[2];
    const float* lamb_l_h = (const float*)d_in[3];
    const float* lamb_h_h = (const float*)d_in[4];
    const float* conv_v   = (const float*)d_in[5];
    const float* inside_v = (const float*)d_in[6];
    const float* lamb_l_v = (const float*)d_in[7];
    const float* lamb_h_v = (const float*)d_in[8];
    const float* gamma    = (const float*)d_in[9];
    const float* beta     = (const float*)d_in[10];
    float* out = (float*)d_out;

    float* ws = (float*)d_ws;
    float* rowsum   = ws;                 // NC*HH = 131072
    float* colsum   = ws + 131072;        // NC*WW = 131072
    float* planesum = ws + 262144;        // NC    = 512
    float* f_h      = ws + 262656;        // 80
    float* f_v      = ws + 262736;        // 80

    k_reduce<<<NC, 256, 0, stream>>>((const float4*)x, rowsum, colsum, planesum);
    k_small<<<1, 256, 0, stream>>>(colsum, planesum, conv_h, inside_h, lamb_l_h,
                                   lamb_h_h, conv_v, f_h, f_v);
    k_main<<<NC * 4, 256, 0, stream>>>(x, rowsum, colsum, planesum, f_h, f_v,
                                       inside_h, lamb_l_h, lamb_h_h,
                                       inside_v, lamb_l_v, lamb_h_v,
                                       gamma, beta, out);
}